// Round 1
// baseline (611.435 us; speedup 1.0000x reference)
//
#include <hip/hip_runtime.h>

#define LATENT 128
#define HEAD 8
#define DH 16
#define TM 32   // rows per block in GEMM

// ---------------------------------------------------------------------------
// Kernel 1: QKV projection.  out[r][c] = sum_k emb[r][k] * W[k][c]
// gridDim.y = 3 selects (Wq->Q, Wk->K, Wv->V).
// LDS: full W (64 KB, natural layout) + TM x 128 emb tile (16 KB).
// Each thread computes a 4x4 register tile (rows r0..r0+3, cols c0..c0+3).
// ---------------------------------------------------------------------------
__global__ __launch_bounds__(256) void qkv_gemm(
    const float* __restrict__ emb,
    const float* __restrict__ Wq, const float* __restrict__ Wk, const float* __restrict__ Wv,
    float* __restrict__ Q, float* __restrict__ K, float* __restrict__ V,
    int nNodes)
{
    __shared__ float sW[LATENT * LATENT];     // 64 KB
    __shared__ float sE[TM][LATENT];          // 16 KB

    const float* W;
    float* out;
    if (blockIdx.y == 0)      { W = Wq; out = Q; }
    else if (blockIdx.y == 1) { W = Wk; out = K; }
    else                      { W = Wv; out = V; }

    const int tid  = threadIdx.x;
    const int row0 = blockIdx.x * TM;

    // stage W (16384 floats = 4096 float4)
    for (int i = tid; i < LATENT * LATENT / 4; i += 256)
        ((float4*)sW)[i] = ((const float4*)W)[i];

    // stage emb tile (TM*128 floats = TM*32 float4)
    for (int i = tid; i < TM * LATENT / 4; i += 256) {
        int r  = i >> 5;       // 32 float4 per row
        int c4 = i & 31;
        int gr = row0 + r;
        float4 v = make_float4(0.f, 0.f, 0.f, 0.f);
        if (gr < nNodes) v = ((const float4*)emb)[gr * (LATENT / 4) + c4];
        ((float4*)&sE[r][0])[c4] = v;
    }
    __syncthreads();

    const int c0 = (tid & 31) * 4;
    const int r0 = (tid >> 5) * 4;

    float acc[4][4] = {};
#pragma unroll 8
    for (int k = 0; k < LATENT; ++k) {
        float4 w4 = *(const float4*)&sW[k * LATENT + c0];
        float e0 = sE[r0 + 0][k];
        float e1 = sE[r0 + 1][k];
        float e2 = sE[r0 + 2][k];
        float e3 = sE[r0 + 3][k];
        acc[0][0] += e0 * w4.x; acc[0][1] += e0 * w4.y; acc[0][2] += e0 * w4.z; acc[0][3] += e0 * w4.w;
        acc[1][0] += e1 * w4.x; acc[1][1] += e1 * w4.y; acc[1][2] += e1 * w4.z; acc[1][3] += e1 * w4.w;
        acc[2][0] += e2 * w4.x; acc[2][1] += e2 * w4.y; acc[2][2] += e2 * w4.z; acc[2][3] += e2 * w4.w;
        acc[3][0] += e3 * w4.x; acc[3][1] += e3 * w4.y; acc[3][2] += e3 * w4.z; acc[3][3] += e3 * w4.w;
    }

#pragma unroll
    for (int r = 0; r < 4; ++r) {
        int gr = row0 + r0 + r;
        if (gr < nNodes) {
            float4 o = make_float4(acc[r][0], acc[r][1], acc[r][2], acc[r][3]);
            *(float4*)&out[gr * LATENT + c0] = o;
        }
    }
}

// ---------------------------------------------------------------------------
// Kernel 2: per-(edge,head) attention score.
// expAtt (written into the att output region) = exp(clip(q.k, -10, 10))
// norm[row][h] += expAtt   (atomic)
// ---------------------------------------------------------------------------
__global__ __launch_bounds__(256) void edge_scores(
    const float* __restrict__ Q, const float* __restrict__ K,
    const int* __restrict__ rows, const int* __restrict__ cols,
    float* __restrict__ expAtt, float* __restrict__ norm, int nEdges)
{
    int t = blockIdx.x * 256 + threadIdx.x;
    int e = t >> 3;
    int h = t & 7;
    if (e >= nEdges) return;
    int r = rows[e];
    int c = cols[e];

    const float4* q4 = (const float4*)&Q[r * LATENT + h * DH];
    const float4* k4 = (const float4*)&K[c * LATENT + h * DH];
    float s = 0.f;
#pragma unroll
    for (int i = 0; i < 4; ++i) {
        float4 a = q4[i];
        float4 b = k4[i];
        s += a.x * b.x + a.y * b.y + a.z * b.z + a.w * b.w;
    }
    s = fminf(fmaxf(s, -10.f), 10.f);
    float ex = expf(s);
    expAtt[e * HEAD + h] = ex;
    atomicAdd(&norm[r * HEAD + h], ex);
}

// ---------------------------------------------------------------------------
// Kernel 3: normalize att in place + aggregate weighted V into resEmbeds.
// One thread per (edge, d); 128 threads (2 waves) per edge.
// ---------------------------------------------------------------------------
__global__ __launch_bounds__(256) void edge_aggregate(
    const float* __restrict__ V,
    const int* __restrict__ rows, const int* __restrict__ cols,
    const float* __restrict__ norm,
    float* __restrict__ att,           // in: expAtt, out: normalized att
    float* __restrict__ outEmb, int nEdges)
{
    int t = blockIdx.x * 256 + threadIdx.x;
    int e = t >> 7;
    int d = t & 127;
    if (e >= nEdges) return;
    int h = d >> 4;
    int r = rows[e];
    int c = cols[e];

    float ex = att[e * HEAD + h];
    float nm = norm[r * HEAD + h];
    float a  = ex / (nm + 1e-8f);
    // all lanes of this (e,h) group read before this lane stores (in-wave order)
    if ((d & 15) == 0) att[e * HEAD + h] = a;

    float v = V[c * LATENT + d];
    atomicAdd(&outEmb[r * LATENT + d], a * v);
}

// ---------------------------------------------------------------------------
extern "C" void kernel_launch(void* const* d_in, const int* in_sizes, int n_in,
                              void* d_out, int out_size, void* d_ws, size_t ws_size,
                              hipStream_t stream)
{
    const float* emb = (const float*)d_in[0];
    const int*   rows = (const int*)d_in[1];
    const int*   cols = (const int*)d_in[2];
    const float* Wq = (const float*)d_in[3];
    const float* Wk = (const float*)d_in[4];
    const float* Wv = (const float*)d_in[5];

    const int N = in_sizes[0] / LATENT;   // 50000
    const int E = in_sizes[1];            // 800000

    float* outEmb = (float*)d_out;                         // [N,128]
    float* attOut = (float*)d_out + (size_t)N * LATENT;    // [E,8]

    float* Q    = (float*)d_ws;
    float* K    = Q + (size_t)N * LATENT;
    float* V    = K + (size_t)N * LATENT;
    float* norm = V + (size_t)N * LATENT;                  // [N,8]

    // zero accumulators (capture-legal async memsets)
    hipMemsetAsync(outEmb, 0, (size_t)N * LATENT * sizeof(float), stream);
    hipMemsetAsync(norm, 0, (size_t)N * HEAD * sizeof(float), stream);

    // 1. QKV projections
    dim3 gGemm((N + TM - 1) / TM, 3);
    qkv_gemm<<<gGemm, 256, 0, stream>>>(emb, Wq, Wk, Wv, Q, K, V, N);

    // 2. per-edge scores + softmax denominator
    int tScores = E * HEAD;
    edge_scores<<<(tScores + 255) / 256, 256, 0, stream>>>(Q, K, rows, cols,
                                                           attOut, norm, E);

    // 3. normalize + aggregate
    long long tAgg = (long long)E * LATENT;
    edge_aggregate<<<(int)((tAgg + 255) / 256), 256, 0, stream>>>(V, rows, cols,
                                                                  norm, attOut,
                                                                  outEmb, E);
}